// Round 6
// baseline (675.583 us; speedup 1.0000x reference)
//
#include <hip/hip_runtime.h>

#define THREADS 256
#define SBLK 512

typedef __attribute__((ext_vector_type(8))) short short8;
typedef __attribute__((ext_vector_type(4))) float f32x4;

__device__ __forceinline__ unsigned short f2bf(float f) {
    unsigned u = __builtin_bit_cast(unsigned, f);
    return (unsigned short)((u + 0x7FFFu + ((u >> 16) & 1u)) >> 16);  // RNE
}
__device__ __forceinline__ float bf2f_lo(unsigned u) { return __builtin_bit_cast(float, u << 16); }
__device__ __forceinline__ float bf2f_hi(unsigned u) { return __builtin_bit_cast(float, u & 0xFFFF0000u); }

__device__ __forceinline__ int group_of(int r, int n_nodes) {
    return (int)(((long long)r * 8) / n_nodes);
}
__device__ __forceinline__ int group_lo(int g, int n_nodes) {
    return (int)((((long long)g * n_nodes) + 7) >> 3);  // ceil(g*N/8)
}

// ---------------- generic helpers ----------------

__global__ void zero_kernel(int* __restrict__ p, int n) {
    int i = blockIdx.x * blockDim.x + threadIdx.x;
    if (i < n) p[i] = 0;
}

__global__ void init_gcur_kernel(int* __restrict__ gcur, int cap) {
    int i = threadIdx.x;
    if (i < 8) gcur[i] = i * cap;
}

// ---------------- NEW: single-read edge staging into 8 XCD-owned regions ----------------
// Block owns a contiguous edge range. Pass 1: per-thread per-group counts in LDS.
// Vector-scan (8 groups at once) over the 256 threads -> per-thread bases;
// one global atomicAdd per group per block reserves a chunk. Pass 2: re-read
// edges, write packed records (rl<<17|col, val) to group regions.
__global__ void stage_kernel(const int* __restrict__ row, const int* __restrict__ col,
                             const float* __restrict__ val, int* __restrict__ gcur,
                             uint2* __restrict__ estage, int* __restrict__ cnt,
                             int n_edges, int n_nodes, int cap) {
    __shared__ int sc[2][256][8];
    __shared__ int gchunk[8];
    int tid = threadIdx.x;
    int bid = blockIdx.x;

    // zero a slice of cnt (so hist_g can atomicAdd later)
    int cz = (n_nodes + SBLK - 1) / SBLK;
    int zend = (bid + 1) * cz; if (zend > n_nodes) zend = n_nodes;
    for (int i = bid * cz + tid; i < zend; i += THREADS) cnt[i] = 0;

    int E0 = (int)((long long)bid * n_edges / SBLK);
    int E1 = (int)((long long)(bid + 1) * n_edges / SBLK);

    #pragma unroll
    for (int g = 0; g < 8; ++g) sc[0][tid][g] = 0;
    for (int e = E0 + tid; e < E1; e += THREADS) {
        int g = group_of(row[e], n_nodes);
        sc[0][tid][g]++;
    }
    __syncthreads();

    int cb = 0;
    for (int off = 1; off < 256; off <<= 1) {
        #pragma unroll
        for (int g = 0; g < 8; ++g) {
            int v = sc[cb][tid][g];
            if (tid >= off) v += sc[cb][tid - off][g];
            sc[cb ^ 1][tid][g] = v;
        }
        cb ^= 1;
        __syncthreads();
    }
    // sc[cb] now holds inclusive scans
    if (tid < 8) {
        int tot = sc[cb][255][tid];
        gchunk[tid] = atomicAdd(&gcur[tid], tot);
    }
    __syncthreads();
    int cbw = cb ^ 1;  // cursor buffer
    #pragma unroll
    for (int g = 0; g < 8; ++g)
        sc[cbw][tid][g] = gchunk[g] + (tid ? sc[cb][tid - 1][g] : 0);
    // (each thread only touches its own cursor slot from here on)
    for (int e = E0 + tid; e < E1; e += THREADS) {
        int r = row[e];
        int g = group_of(r, n_nodes);
        int lo = group_lo(g, n_nodes);
        int pos = sc[cbw][tid][g]++;
        if (pos < (g + 1) * cap)  // overflow guard (statistically never)
            estage[pos] = make_uint2(((unsigned)(r - lo) << 17) | (unsigned)col[e],
                                     (unsigned)__float_as_int(val[e]));
    }
}

// hist from staged records: group g = blockIdx&7 reads its XCD-local region.
__global__ void hist_g_kernel(const uint2* __restrict__ estage, const int* __restrict__ gcur,
                              int* __restrict__ cnt, int cap, int n_nodes) {
    int g = blockIdx.x & 7;
    int inst = blockIdx.x >> 3;
    int ninst = gridDim.x >> 3;
    int base = g * cap;
    int count = gcur[g] - base; if (count > cap) count = cap;
    int i0 = (int)((long long)inst * count / ninst);
    int i1 = (int)((long long)(inst + 1) * count / ninst);
    int lo = group_lo(g, n_nodes);
    for (int i = base + i0 + threadIdx.x; i < base + i1; i += THREADS) {
        unsigned p = estage[i].x;
        atomicAdd(&cnt[lo + (int)(p >> 17)], 1);
    }
}

// CSR place from staged records (XCD-local reads + writes).
__global__ void place_g_kernel(const uint2* __restrict__ estage, const int* __restrict__ gcur,
                               int* __restrict__ cur, int2* __restrict__ pr,
                               int cap, int n_nodes) {
    int g = blockIdx.x & 7;
    int inst = blockIdx.x >> 3;
    int ninst = gridDim.x >> 3;
    int base = g * cap;
    int count = gcur[g] - base; if (count > cap) count = cap;
    int i0 = (int)((long long)inst * count / ninst);
    int i1 = (int)((long long)(inst + 1) * count / ninst);
    int lo = group_lo(g, n_nodes);
    for (int i = base + i0 + threadIdx.x; i < base + i1; i += THREADS) {
        uint2 p = estage[i];
        int r = lo + (int)(p.x >> 17);
        int q = atomicAdd(&cur[r], 1);
        pr[q] = make_int2((int)(p.x & 0x1FFFFu), (int)p.y);
    }
}

// ---------------- OLD CSR build (fallback tiers) ----------------

__global__ void hist_part_kernel(const int* __restrict__ row, int* __restrict__ cnt,
                                 int n_edges, int n_nodes) {
    int g = blockIdx.x & 7;
    int inst = blockIdx.x >> 3;
    int ninst = gridDim.x >> 3;
    int lo = (int)(((long long)g * n_nodes) >> 3);
    int hi = (int)(((long long)(g + 1) * n_nodes) >> 3);
    int e0 = (int)(((long long)inst * n_edges) / ninst);
    int e1 = (int)(((long long)(inst + 1) * n_edges) / ninst);
    for (int e = e0 + threadIdx.x; e < e1; e += THREADS) {
        int r = row[e];
        if (r >= lo && r < hi) atomicAdd(&cnt[r], 1);
    }
}

__global__ void place_part_kernel(const int* __restrict__ row, const int* __restrict__ col,
                                  const float* __restrict__ val, int* __restrict__ cur,
                                  int2* __restrict__ pr, int n_edges, int n_nodes) {
    int g = blockIdx.x & 7;
    int inst = blockIdx.x >> 3;
    int ninst = gridDim.x >> 3;
    int lo = (int)(((long long)g * n_nodes) >> 3);
    int hi = (int)(((long long)(g + 1) * n_nodes) >> 3);
    int e0 = (int)(((long long)inst * n_edges) / ninst);
    int e1 = (int)(((long long)(inst + 1) * n_edges) / ninst);
    for (int e = e0 + threadIdx.x; e < e1; e += THREADS) {
        int r = row[e];
        if (r >= lo && r < hi) {
            int p = atomicAdd(&cur[r], 1);
            pr[p] = make_int2(col[e], __float_as_int(val[e]));
        }
    }
}

// ---------------- scans ----------------

__global__ void scan1_kernel(const int* __restrict__ cnt, int* __restrict__ offs,
                             int* __restrict__ bsum, int n) {
    int tid = threadIdx.x;
    int base = blockIdx.x * 1024 + tid * 4;
    int v0 = 0, v1 = 0, v2 = 0, v3 = 0;
    if (base + 3 < n) {
        int4 v = *reinterpret_cast<const int4*>(cnt + base);
        v0 = v.x; v1 = v.y; v2 = v.z; v3 = v.w;
    } else {
        if (base + 0 < n) v0 = cnt[base + 0];
        if (base + 1 < n) v1 = cnt[base + 1];
        if (base + 2 < n) v2 = cnt[base + 2];
    }
    int ts = v0 + v1 + v2 + v3;
    int lane = tid & 63;
    int incl = ts;
    #pragma unroll
    for (int off = 1; off < 64; off <<= 1) {
        int t = __shfl_up(incl, off, 64);
        if (lane >= off) incl += t;
    }
    __shared__ int wsum[4];
    int w = tid >> 6;
    if (lane == 63) wsum[w] = incl;
    __syncthreads();
    int wo = 0;
    for (int i = 0; i < w; ++i) wo += wsum[i];
    int excl = wo + incl - ts;
    if (base + 0 < n) offs[base + 0] = excl;
    if (base + 1 < n) offs[base + 1] = excl + v0;
    if (base + 2 < n) offs[base + 2] = excl + v0 + v1;
    if (base + 3 < n) offs[base + 3] = excl + v0 + v1 + v2;
    if (tid == THREADS - 1) bsum[blockIdx.x] = wo + incl;
}

__global__ void scan2_kernel(int* __restrict__ bsum, int nb) {
    int tid = threadIdx.x;
    int base = tid * 4;
    int v0 = 0, v1 = 0, v2 = 0, v3 = 0;
    if (base + 0 < nb) v0 = bsum[base + 0];
    if (base + 1 < nb) v1 = bsum[base + 1];
    if (base + 2 < nb) v2 = bsum[base + 2];
    if (base + 3 < nb) v3 = bsum[base + 3];
    int ts = v0 + v1 + v2 + v3;
    int lane = tid & 63;
    int incl = ts;
    #pragma unroll
    for (int off = 1; off < 64; off <<= 1) {
        int t = __shfl_up(incl, off, 64);
        if (lane >= off) incl += t;
    }
    __shared__ int wsum[4];
    int w = tid >> 6;
    if (lane == 63) wsum[w] = incl;
    __syncthreads();
    int wo = 0;
    for (int i = 0; i < w; ++i) wo += wsum[i];
    int excl = wo + incl - ts;
    if (base + 0 < nb) bsum[base + 0] = excl;
    if (base + 1 < nb) bsum[base + 1] = excl + v0;
    if (base + 2 < nb) bsum[base + 2] = excl + v0 + v1;
    if (base + 3 < nb) bsum[base + 3] = excl + v0 + v1 + v2;
    if (tid == THREADS - 1) bsum[nb] = wo + incl;
}

__global__ void scan3_kernel(int* __restrict__ offs, const int* __restrict__ bsum,
                             int* __restrict__ cur, int n) {
    int i = blockIdx.x * blockDim.x + threadIdx.x;
    if (i < n) {
        int v = offs[i] + bsum[i >> 10];
        offs[i] = v;
        cur[i] = v;
    }
    if (i == 0) offs[n] = bsum[(n + 1023) >> 10];
}

// ---------------- converts ----------------

__global__ void cvt_bf16_kernel(const float4* __restrict__ in, uint4* __restrict__ out, int n8) {
    int i = blockIdx.x * blockDim.x + threadIdx.x;
    if (i >= n8) return;
    float4 a = in[2 * i], b = in[2 * i + 1];
    uint4 o;
    o.x = (unsigned)f2bf(a.x) | ((unsigned)f2bf(a.y) << 16);
    o.y = (unsigned)f2bf(a.z) | ((unsigned)f2bf(a.w) << 16);
    o.z = (unsigned)f2bf(b.x) | ((unsigned)f2bf(b.y) << 16);
    o.w = (unsigned)f2bf(b.z) | ((unsigned)f2bf(b.w) << 16);
    out[i] = o;
}

// W (f32 [256][256]) -> MFMA B-fragment order (bf16):
// frag f = (k0i*16+nt)*64 + lane holds W[nt*16+(lane&15)][k0i*32 + 8*(lane>>4) .. +7]
__global__ void cvt_W_pack_kernel(const float* __restrict__ W, unsigned short* __restrict__ WbP) {
    int f = blockIdx.x * blockDim.x + threadIdx.x;
    if (f >= 8192) return;
    int l = f & 63, nt = (f >> 6) & 15, k0i = f >> 10;
    int r = nt * 16 + (l & 15);
    int koff = k0i * 32 + 8 * (l >> 4);
    const float4* s = reinterpret_cast<const float4*>(W + r * 256 + koff);
    float4 a = s[0], b = s[1];
    uint4 o;
    o.x = (unsigned)f2bf(a.x) | ((unsigned)f2bf(a.y) << 16);
    o.y = (unsigned)f2bf(a.z) | ((unsigned)f2bf(a.w) << 16);
    o.z = (unsigned)f2bf(b.x) | ((unsigned)f2bf(b.y) << 16);
    o.w = (unsigned)f2bf(b.z) | ((unsigned)f2bf(b.w) << 16);
    reinterpret_cast<uint4*>(WbP)[f] = o;
}

// ---------------- SpMM: one wave64 per node, bf16 gathers, x8 unroll ----------------
// OUT_BF16=1: write bf16 agg rows to ws; OUT_BF16=0: write f32 to d_out.
template<int OUT_BF16>
__global__ void spmm_bf16_kernel(const uint2* __restrict__ xb, const int* __restrict__ offs,
                                 const int2* __restrict__ pr, void* __restrict__ outp,
                                 int nnodes) {
    int wid = (blockIdx.x * blockDim.x + threadIdx.x) >> 6;
    int lane = threadIdx.x & 63;
    if (wid >= nnodes) return;
    int s = offs[wid], e = offs[wid + 1];
    float a0 = 0.f, a1 = 0.f, a2 = 0.f, a3 = 0.f;
    int i = s;
    if (i < e && (i & 1)) {
        int2 p = pr[i];
        uint2 xv = xb[(size_t)p.x * 64 + lane];
        float v = __int_as_float(p.y);
        a0 = fmaf(v, bf2f_lo(xv.x), a0); a1 = fmaf(v, bf2f_hi(xv.x), a1);
        a2 = fmaf(v, bf2f_lo(xv.y), a2); a3 = fmaf(v, bf2f_hi(xv.y), a3);
        ++i;
    }
    for (; i + 8 <= e; i += 8) {
        int4 pa = *reinterpret_cast<const int4*>(pr + i);
        int4 pb = *reinterpret_cast<const int4*>(pr + i + 2);
        int4 pc = *reinterpret_cast<const int4*>(pr + i + 4);
        int4 pd = *reinterpret_cast<const int4*>(pr + i + 6);
        uint2 x0 = xb[(size_t)pa.x * 64 + lane];
        uint2 x1 = xb[(size_t)pa.z * 64 + lane];
        uint2 x2 = xb[(size_t)pb.x * 64 + lane];
        uint2 x3 = xb[(size_t)pb.z * 64 + lane];
        uint2 x4_ = xb[(size_t)pc.x * 64 + lane];
        uint2 x5 = xb[(size_t)pc.z * 64 + lane];
        uint2 x6 = xb[(size_t)pd.x * 64 + lane];
        uint2 x7 = xb[(size_t)pd.z * 64 + lane];
        float v0 = __int_as_float(pa.y), v1 = __int_as_float(pa.w);
        float v2 = __int_as_float(pb.y), v3 = __int_as_float(pb.w);
        float v4 = __int_as_float(pc.y), v5 = __int_as_float(pc.w);
        float v6 = __int_as_float(pd.y), v7 = __int_as_float(pd.w);
        a0 = fmaf(v0, bf2f_lo(x0.x), a0); a1 = fmaf(v0, bf2f_hi(x0.x), a1);
        a2 = fmaf(v0, bf2f_lo(x0.y), a2); a3 = fmaf(v0, bf2f_hi(x0.y), a3);
        a0 = fmaf(v1, bf2f_lo(x1.x), a0); a1 = fmaf(v1, bf2f_hi(x1.x), a1);
        a2 = fmaf(v1, bf2f_lo(x1.y), a2); a3 = fmaf(v1, bf2f_hi(x1.y), a3);
        a0 = fmaf(v2, bf2f_lo(x2.x), a0); a1 = fmaf(v2, bf2f_hi(x2.x), a1);
        a2 = fmaf(v2, bf2f_lo(x2.y), a2); a3 = fmaf(v2, bf2f_hi(x2.y), a3);
        a0 = fmaf(v3, bf2f_lo(x3.x), a0); a1 = fmaf(v3, bf2f_hi(x3.x), a1);
        a2 = fmaf(v3, bf2f_lo(x3.y), a2); a3 = fmaf(v3, bf2f_hi(x3.y), a3);
        a0 = fmaf(v4, bf2f_lo(x4_.x), a0); a1 = fmaf(v4, bf2f_hi(x4_.x), a1);
        a2 = fmaf(v4, bf2f_lo(x4_.y), a2); a3 = fmaf(v4, bf2f_hi(x4_.y), a3);
        a0 = fmaf(v5, bf2f_lo(x5.x), a0); a1 = fmaf(v5, bf2f_hi(x5.x), a1);
        a2 = fmaf(v5, bf2f_lo(x5.y), a2); a3 = fmaf(v5, bf2f_hi(x5.y), a3);
        a0 = fmaf(v6, bf2f_lo(x6.x), a0); a1 = fmaf(v6, bf2f_hi(x6.x), a1);
        a2 = fmaf(v6, bf2f_lo(x6.y), a2); a3 = fmaf(v6, bf2f_hi(x6.y), a3);
        a0 = fmaf(v7, bf2f_lo(x7.x), a0); a1 = fmaf(v7, bf2f_hi(x7.x), a1);
        a2 = fmaf(v7, bf2f_lo(x7.y), a2); a3 = fmaf(v7, bf2f_hi(x7.y), a3);
    }
    for (; i + 2 <= e; i += 2) {
        int4 pa = *reinterpret_cast<const int4*>(pr + i);
        uint2 x0 = xb[(size_t)pa.x * 64 + lane];
        uint2 x1 = xb[(size_t)pa.z * 64 + lane];
        float v0 = __int_as_float(pa.y), v1 = __int_as_float(pa.w);
        a0 = fmaf(v0, bf2f_lo(x0.x), a0); a1 = fmaf(v0, bf2f_hi(x0.x), a1);
        a2 = fmaf(v0, bf2f_lo(x0.y), a2); a3 = fmaf(v0, bf2f_hi(x0.y), a3);
        a0 = fmaf(v1, bf2f_lo(x1.x), a0); a1 = fmaf(v1, bf2f_hi(x1.x), a1);
        a2 = fmaf(v1, bf2f_lo(x1.y), a2); a3 = fmaf(v1, bf2f_hi(x1.y), a3);
    }
    for (; i < e; ++i) {
        int2 p = pr[i];
        uint2 xv = xb[(size_t)p.x * 64 + lane];
        float v = __int_as_float(p.y);
        a0 = fmaf(v, bf2f_lo(xv.x), a0); a1 = fmaf(v, bf2f_hi(xv.x), a1);
        a2 = fmaf(v, bf2f_lo(xv.y), a2); a3 = fmaf(v, bf2f_hi(xv.y), a3);
    }
    if (OUT_BF16) {
        ushort4 o;
        o.x = f2bf(a0); o.y = f2bf(a1); o.z = f2bf(a2); o.w = f2bf(a3);
        *reinterpret_cast<ushort4*>((unsigned short*)outp + (size_t)wid * 256 + 4 * lane) = o;
    } else {
        ((float4*)outp)[(size_t)wid * 64 + lane] = make_float4(a0, a1, a2, a3);
    }
}

// f32 fallback (small ws)
__global__ void spmm_f32_kernel(const float4* __restrict__ x4, const int* __restrict__ offs,
                                const int2* __restrict__ pr, float4* __restrict__ out4,
                                int nnodes) {
    int wid = (blockIdx.x * blockDim.x + threadIdx.x) >> 6;
    int lane = threadIdx.x & 63;
    if (wid >= nnodes) return;
    int s = offs[wid], e = offs[wid + 1];
    float4 acc = make_float4(0.f, 0.f, 0.f, 0.f);
    for (int i = s; i < e; ++i) {
        int2 p = pr[i];
        float4 xv = x4[(size_t)p.x * 64 + lane];
        float v = __int_as_float(p.y);
        acc.x = fmaf(v, xv.x, acc.x); acc.y = fmaf(v, xv.y, acc.y);
        acc.z = fmaf(v, xv.z, acc.z); acc.w = fmaf(v, xv.w, acc.w);
    }
    out4[(size_t)wid * 64 + lane] = acc;
}

// ---------------- NEW: LDS-free direct MFMA GEMM (bf16 agg -> f32 out) ----------------
// Wave w handles rows [blk*64 + w*16, +16). A-frags straight from global bf16
// agg; B-frags from fragment-ordered WbP (L2-hot). No LDS, no barriers.
__launch_bounds__(256)
__global__ void gemm_direct_kernel(const unsigned short* __restrict__ aggb,
                                   const unsigned short* __restrict__ WbP,
                                   const float* __restrict__ bias,
                                   float* __restrict__ out, int n) {
    int tid = threadIdx.x, lane = tid & 63, w = tid >> 6;
    int row0 = blockIdx.x * 64 + w * 16;
    int lr = lane & 15, lg = lane >> 4;
    const unsigned short* arow = aggb + (size_t)(row0 + lr) * 256 + lg * 8;
    short8 af[8];
    #pragma unroll
    for (int k = 0; k < 8; ++k)
        af[k] = *reinterpret_cast<const short8*>(arow + k * 32);
    f32x4 acc[16];
    #pragma unroll
    for (int nt = 0; nt < 16; ++nt) acc[nt] = (f32x4){0.f, 0.f, 0.f, 0.f};
    #pragma unroll
    for (int k = 0; k < 8; ++k) {
        #pragma unroll
        for (int nt = 0; nt < 16; ++nt) {
            short8 bf_ = *reinterpret_cast<const short8*>(
                &WbP[(size_t)((k * 16 + nt) * 64 + lane) * 8]);
            acc[nt] = __builtin_amdgcn_mfma_f32_16x16x32_bf16(af[k], bf_, acc[nt], 0, 0, 0);
        }
    }
    #pragma unroll
    for (int nt = 0; nt < 16; ++nt) {
        int gc = nt * 16 + lr;
        float bv = bias[gc];
        #pragma unroll
        for (int q = 0; q < 4; ++q) {
            int gr = row0 + lg * 4 + q;
            if (gr < n) out[(size_t)gr * 256 + gc] = acc[nt][q] + bv;
        }
    }
}

// ---------------- in-place GEMM (fallback tiers; f32 agg lives in d_out) ----------------
__launch_bounds__(256, 2)
__global__ void gemm_mfma_kernel(float* __restrict__ out, const unsigned short* __restrict__ Wb,
                                 const float* __restrict__ bias, int nrows) {
    __shared__ unsigned short As[64][264];
    __shared__ unsigned short Ws[256][40];
    int tid = threadIdx.x;
    int rowBase = blockIdx.x * 64;

    const float4* o4 = reinterpret_cast<const float4*>(out);
    for (int it = tid; it < 64 * 64; it += 256) {
        int r = it >> 6, c = it & 63;
        float4 v = make_float4(0.f, 0.f, 0.f, 0.f);
        int gr = rowBase + r;
        if (gr < nrows) v = o4[(size_t)gr * 64 + c];
        ushort4 w;
        w.x = f2bf(v.x); w.y = f2bf(v.y); w.z = f2bf(v.z); w.w = f2bf(v.w);
        *reinterpret_cast<ushort4*>(&As[r][c * 4]) = w;
    }

    int w = tid >> 6, lane = tid & 63;
    int lr = lane & 15, lg = lane >> 4;
    f32x4 acc[16];
    #pragma unroll
    for (int nt = 0; nt < 16; ++nt) acc[nt] = (f32x4){0.f, 0.f, 0.f, 0.f};

    for (int k0 = 0; k0 < 256; k0 += 32) {
        __syncthreads();
        for (int it = tid; it < 1024; it += 256) {
            int r = it >> 2, c = it & 3;
            uint4 v = *reinterpret_cast<const uint4*>(Wb + (size_t)r * 256 + k0 + c * 8);
            *reinterpret_cast<uint4*>(&Ws[r][c * 8]) = v;
        }
        __syncthreads();
        short8 af = *reinterpret_cast<const short8*>(&As[w * 16 + lr][k0 + 8 * lg]);
        #pragma unroll
        for (int nt = 0; nt < 16; ++nt) {
            short8 bf_ = *reinterpret_cast<const short8*>(&Ws[nt * 16 + lr][8 * lg]);
            acc[nt] = __builtin_amdgcn_mfma_f32_16x16x32_bf16(af, bf_, acc[nt], 0, 0, 0);
        }
    }

    #pragma unroll
    for (int nt = 0; nt < 16; ++nt) {
        int gc = nt * 16 + lr;
        float bv = bias[gc];
        #pragma unroll
        for (int q = 0; q < 4; ++q) {
            int gr = rowBase + w * 16 + lg * 4 + q;
            if (gr < nrows) out[(size_t)gr * 256 + gc] = acc[nt][q] + bv;
        }
    }
}

// ---------------- launch ----------------

extern "C" void kernel_launch(void* const* d_in, const int* in_sizes, int n_in,
                              void* d_out, int out_size, void* d_ws, size_t ws_size,
                              hipStream_t stream) {
    const float* x     = (const float*)d_in[0];
    const int*   erow  = (const int*)d_in[1];
    const int*   ecol  = (const int*)d_in[2];
    const float* evalv = (const float*)d_in[3];
    const float* W     = (const float*)d_in[4];
    const float* bias  = (const float*)d_in[5];
    float* out = (float*)d_out;

    int n_nodes = in_sizes[0] / 256;
    int n_edges = in_sizes[1];
    int nb = (n_nodes + 1023) >> 10;

    int cap = (n_edges + 7) / 8 + 16384;          // per-group staging capacity
    size_t capT = (size_t)cap * 8;                // records total

    // ---- workspace layout (int units) ----
    size_t A = (size_t)((n_nodes + 63) & ~63);
    int* cnt  = (int*)d_ws;
    int* offs = cnt + A;
    int* cur  = offs + A;
    int* bsum = cur + A;                       // nb+1, pad 256
    int* gcur = bsum + 256;                    // 8, pad 64
    unsigned short* Wb  = (unsigned short*)(gcur + 64);  // 32768 ints
    unsigned short* WbP = Wb + 65536;                    // 32768 ints
    int* tail = (int*)(WbP + 65536);
    int2* pr = (int2*)tail;                    // 2E ints
    int* after_pr = tail + 2 * (size_t)n_edges;

    size_t est_ints  = 2 * capT;               // estage record = uint2
    size_t aggb_ints = (size_t)n_nodes * 64;   // n*256 bf16 = n*128 shorts? no: n*256 shorts = n*128 ints
    aggb_ints = (size_t)n_nodes * 128;
    size_t xb_ints   = (size_t)n_nodes * 128;

    size_t head_ints = (size_t)(after_pr - (int*)d_ws);
    size_t alias2 = est_ints > aggb_ints ? est_ints : aggb_ints;
    size_t need2   = (head_ints + alias2 + xb_ints) * 4;        // new CSR + bf16 agg
    size_t needmid = (head_ints + est_ints + xb_ints) * 4;      // new CSR + f32 agg in d_out
    size_t needold = (head_ints + xb_ints) * 4;                 // old CSR + bf16 spmm
    bool pack_ok = (n_nodes <= 131072) && (cap <= (1 << 24));

    bool t2   = pack_ok && ws_size >= need2;
    bool tmid = pack_ok && ws_size >= needmid;
    bool told = ws_size >= needold;

    if (t2 || tmid) {
        // -------- new single-read CSR build --------
        uint2* estage = (uint2*)after_pr;
        init_gcur_kernel<<<1, 64, 0, stream>>>(gcur, cap);
        stage_kernel<<<SBLK, THREADS, 0, stream>>>(erow, ecol, evalv, gcur, estage,
                                                   cnt, n_edges, n_nodes, cap);
        hist_g_kernel<<<2048, THREADS, 0, stream>>>(estage, gcur, cnt, cap, n_nodes);
        scan1_kernel<<<nb, THREADS, 0, stream>>>(cnt, offs, bsum, n_nodes);
        scan2_kernel<<<1, THREADS, 0, stream>>>(bsum, nb);
        scan3_kernel<<<(n_nodes + THREADS - 1) / THREADS, THREADS, 0, stream>>>(offs, bsum, cur, n_nodes);
        place_g_kernel<<<2048, THREADS, 0, stream>>>(estage, gcur, cur, pr, cap, n_nodes);

        unsigned short* xb = (unsigned short*)(after_pr + alias2);
        if (!t2) xb = (unsigned short*)(after_pr + est_ints);
        int n8 = n_nodes * 32;
        cvt_bf16_kernel<<<(n8 + THREADS - 1) / THREADS, THREADS, 0, stream>>>(
            (const float4*)x, (uint4*)xb, n8);

        int spmm_blocks = (n_nodes + 3) / 4;
        if (t2) {
            unsigned short* aggb = (unsigned short*)after_pr;  // aliases estage (dead now)
            cvt_W_pack_kernel<<<32, THREADS, 0, stream>>>(W, WbP);
            spmm_bf16_kernel<1><<<spmm_blocks, THREADS, 0, stream>>>(
                (const uint2*)xb, offs, pr, aggb, n_nodes);
            int gb = (n_nodes + 63) / 64;
            gemm_direct_kernel<<<gb, THREADS, 0, stream>>>(aggb, WbP, bias, out, n_nodes);
        } else {
            cvt_bf16_kernel<<<32, THREADS, 0, stream>>>((const float4*)W, (uint4*)Wb, 65536 / 8);
            spmm_bf16_kernel<0><<<spmm_blocks, THREADS, 0, stream>>>(
                (const uint2*)xb, offs, pr, out, n_nodes);
            int gb = (n_nodes + 63) / 64;
            gemm_mfma_kernel<<<gb, THREADS, 0, stream>>>(out, Wb, bias, n_nodes);
        }
    } else {
        // -------- old 8x-read CSR build --------
        zero_kernel<<<(n_nodes + THREADS - 1) / THREADS, THREADS, 0, stream>>>(cnt, n_nodes);
        hist_part_kernel<<<2048, THREADS, 0, stream>>>(erow, cnt, n_edges, n_nodes);
        scan1_kernel<<<nb, THREADS, 0, stream>>>(cnt, offs, bsum, n_nodes);
        scan2_kernel<<<1, THREADS, 0, stream>>>(bsum, nb);
        scan3_kernel<<<(n_nodes + THREADS - 1) / THREADS, THREADS, 0, stream>>>(offs, bsum, cur, n_nodes);
        place_part_kernel<<<2048, THREADS, 0, stream>>>(erow, ecol, evalv, cur, pr, n_edges, n_nodes);
        cvt_bf16_kernel<<<32, THREADS, 0, stream>>>((const float4*)W, (uint4*)Wb, 65536 / 8);

        int gb = (n_nodes + 63) / 64;
        if (told) {
            unsigned short* xb = (unsigned short*)after_pr;
            int n8 = n_nodes * 32;
            cvt_bf16_kernel<<<(n8 + THREADS - 1) / THREADS, THREADS, 0, stream>>>(
                (const float4*)x, (uint4*)xb, n8);
            int spmm_blocks = (n_nodes + 3) / 4;
            spmm_bf16_kernel<0><<<spmm_blocks, THREADS, 0, stream>>>(
                (const uint2*)xb, offs, pr, out, n_nodes);
        } else {
            int spmm_blocks = (n_nodes + 3) / 4;
            spmm_f32_kernel<<<spmm_blocks, THREADS, 0, stream>>>(
                (const float4*)x, offs, pr, (float4*)out, n_nodes);
        }
        gemm_mfma_kernel<<<gb, THREADS, 0, stream>>>(out, Wb, bias, n_nodes);
    }
}

// Round 7
// 439.499 us; speedup vs baseline: 1.5372x; 1.5372x over previous
//
#include <hip/hip_runtime.h>

#define THREADS 256

typedef __attribute__((ext_vector_type(8))) short short8;
typedef __attribute__((ext_vector_type(4))) float f32x4;

__device__ __forceinline__ unsigned short f2bf(float f) {
    unsigned u = __builtin_bit_cast(unsigned, f);
    return (unsigned short)((u + 0x7FFFu + ((u >> 16) & 1u)) >> 16);  // RNE
}
__device__ __forceinline__ float bf2f_lo(unsigned u) { return __builtin_bit_cast(float, u << 16); }
__device__ __forceinline__ float bf2f_hi(unsigned u) { return __builtin_bit_cast(float, u & 0xFFFF0000u); }

// ---------------- NEW: two-level counting sort, zero per-edge global atomics ----------------

__global__ void init_gcur512(int* __restrict__ gcur, int capB) {
    int i = blockIdx.x * blockDim.x + threadIdx.x;
    if (i < 512) gcur[i] = i * capB;
}

// Phase 1: partition edges into node-buckets of 256 nodes.
// Per-block LDS histogram over <=512 buckets; ONE global atomic per (block,bucket)
// reserves a contiguous chunk; per-edge ranks via LDS atomics; scatter packed
// records (rl<<24 | col, val) into bucket regions.
__global__ void p1_sort(const int* __restrict__ row, const int* __restrict__ col,
                        const float* __restrict__ val, int* __restrict__ gcur,
                        uint2* __restrict__ estage, int n_edges, int nbkt, int capB) {
    __shared__ int h[512];
    __shared__ int curl[512];
    int tid = threadIdx.x, bid = blockIdx.x;
    int E0 = (int)((long long)bid * n_edges / gridDim.x);
    int E1 = (int)((long long)(bid + 1) * n_edges / gridDim.x);
    for (int i = tid; i < 512; i += THREADS) h[i] = 0;
    __syncthreads();
    for (int e = E0 + tid; e < E1; e += THREADS)
        atomicAdd(&h[row[e] >> 8], 1);
    __syncthreads();
    for (int b = tid; b < nbkt; b += THREADS) {
        int c = h[b];
        curl[b] = c ? atomicAdd(&gcur[b], c) : 0;
    }
    __syncthreads();
    for (int e = E0 + tid; e < E1; e += THREADS) {
        int r = row[e];
        int b = r >> 8;
        int pos = atomicAdd(&curl[b], 1);   // LDS atomic -> global position
        if (pos < (b + 1) * capB)           // overflow guard (statistically never)
            estage[pos] = make_uint2(((unsigned)(r & 255) << 24) | (unsigned)col[e],
                                     (unsigned)__float_as_int(val[e]));
    }
}

__global__ void bcnt_kernel(const int* __restrict__ gcur, int* __restrict__ bcnt,
                            int capB, int nbkt) {
    int i = blockIdx.x * blockDim.x + threadIdx.x;
    if (i < nbkt) {
        int c = gcur[i] - i * capB;
        bcnt[i] = c > capB ? capB : c;
    }
}

// single-block chunked exclusive scan; offs[0..n], cur[i]=offs[i]
__global__ void bscan_kernel(const int* __restrict__ cnt, int* __restrict__ offs,
                             int* __restrict__ cur, int n) {
    __shared__ int buf[2][THREADS];
    __shared__ int running_s;
    int tid = threadIdx.x;
    if (tid == 0) running_s = 0;
    __syncthreads();
    for (int base = 0; base < n; base += THREADS) {
        int idx = base + tid;
        int v = (idx < n) ? cnt[idx] : 0;
        int incl = v;
        int cb = 0;
        buf[0][tid] = incl;
        __syncthreads();
        #pragma unroll
        for (int off = 1; off < THREADS; off <<= 1) {
            int t = incl;
            if (tid >= off) t += buf[cb][tid - off];
            cb ^= 1;
            buf[cb][tid] = t;
            incl = t;
            __syncthreads();
        }
        int base_run = running_s;
        if (idx < n) {
            int excl = base_run + incl - v;
            offs[idx] = excl;
            cur[idx] = excl;
        }
        int total = buf[cb][THREADS - 1];
        __syncthreads();
        if (tid == 0) running_s = base_run + total;
        __syncthreads();
    }
    if (tid == 0) offs[n] = running_s;
}

// Phase 2: block b sorts its bucket (256 nodes, ~8k edges, L2-resident region)
// into final CSR order and writes the per-node offs directly. All per-edge
// atomics are LDS.
__global__ void p2_sort(const uint2* __restrict__ estage, const int* __restrict__ gcur,
                        const int* __restrict__ bbase, int2* __restrict__ pr,
                        int* __restrict__ offs, int capB, int n_nodes, int n_edges,
                        int nbkt) {
    __shared__ int h[256];
    __shared__ int curh[256];
    __shared__ int wsum[4];
    int b = blockIdx.x, tid = threadIdx.x;
    int base = b * capB;
    int count = gcur[b] - base; if (count > capB) count = capB;
    h[tid] = 0;
    __syncthreads();
    for (int i = tid; i < count; i += THREADS)
        atomicAdd(&h[estage[base + i].x >> 24], 1);
    __syncthreads();
    int v = h[tid];
    int lane = tid & 63, w = tid >> 6;
    int incl = v;
    #pragma unroll
    for (int off = 1; off < 64; off <<= 1) {
        int t = __shfl_up(incl, off, 64);
        if (lane >= off) incl += t;
    }
    if (lane == 63) wsum[w] = incl;
    __syncthreads();
    int wo = 0;
    for (int i = 0; i < w; ++i) wo += wsum[i];
    int excl = wo + incl - v;
    int gb = bbase[b];
    int node = b * 256 + tid;
    if (node < n_nodes) offs[node] = gb + excl;
    curh[tid] = gb + excl;
    if (b == nbkt - 1 && tid == 0) offs[n_nodes] = n_edges;
    __syncthreads();
    for (int i = tid; i < count; i += THREADS) {
        uint2 p = estage[base + i];
        int q = atomicAdd(&curh[(int)(p.x >> 24)], 1);   // LDS atomic
        pr[q] = make_int2((int)(p.x & 0x00FFFFFFu), (int)p.y);
    }
}

// ---------------- OLD CSR build (fallback tier) ----------------

__global__ void zero_kernel(int* __restrict__ p, int n) {
    int i = blockIdx.x * blockDim.x + threadIdx.x;
    if (i < n) p[i] = 0;
}

__global__ void hist_part_kernel(const int* __restrict__ row, int* __restrict__ cnt,
                                 int n_edges, int n_nodes) {
    int g = blockIdx.x & 7;
    int inst = blockIdx.x >> 3;
    int ninst = gridDim.x >> 3;
    int lo = (int)(((long long)g * n_nodes) >> 3);
    int hi = (int)(((long long)(g + 1) * n_nodes) >> 3);
    int e0 = (int)(((long long)inst * n_edges) / ninst);
    int e1 = (int)(((long long)(inst + 1) * n_edges) / ninst);
    for (int e = e0 + threadIdx.x; e < e1; e += THREADS) {
        int r = row[e];
        if (r >= lo && r < hi) atomicAdd(&cnt[r], 1);
    }
}

__global__ void place_part_kernel(const int* __restrict__ row, const int* __restrict__ col,
                                  const float* __restrict__ val, int* __restrict__ cur,
                                  int2* __restrict__ pr, int n_edges, int n_nodes) {
    int g = blockIdx.x & 7;
    int inst = blockIdx.x >> 3;
    int ninst = gridDim.x >> 3;
    int lo = (int)(((long long)g * n_nodes) >> 3);
    int hi = (int)(((long long)(g + 1) * n_nodes) >> 3);
    int e0 = (int)(((long long)inst * n_edges) / ninst);
    int e1 = (int)(((long long)(inst + 1) * n_edges) / ninst);
    for (int e = e0 + threadIdx.x; e < e1; e += THREADS) {
        int r = row[e];
        if (r >= lo && r < hi) {
            int p = atomicAdd(&cur[r], 1);
            pr[p] = make_int2(col[e], __float_as_int(val[e]));
        }
    }
}

__global__ void scan1_kernel(const int* __restrict__ cnt, int* __restrict__ offs,
                             int* __restrict__ bsum, int n) {
    int tid = threadIdx.x;
    int base = blockIdx.x * 1024 + tid * 4;
    int v0 = 0, v1 = 0, v2 = 0, v3 = 0;
    if (base + 3 < n) {
        int4 v = *reinterpret_cast<const int4*>(cnt + base);
        v0 = v.x; v1 = v.y; v2 = v.z; v3 = v.w;
    } else {
        if (base + 0 < n) v0 = cnt[base + 0];
        if (base + 1 < n) v1 = cnt[base + 1];
        if (base + 2 < n) v2 = cnt[base + 2];
    }
    int ts = v0 + v1 + v2 + v3;
    int lane = tid & 63;
    int incl = ts;
    #pragma unroll
    for (int off = 1; off < 64; off <<= 1) {
        int t = __shfl_up(incl, off, 64);
        if (lane >= off) incl += t;
    }
    __shared__ int wsum[4];
    int w = tid >> 6;
    if (lane == 63) wsum[w] = incl;
    __syncthreads();
    int wo = 0;
    for (int i = 0; i < w; ++i) wo += wsum[i];
    int excl = wo + incl - ts;
    if (base + 0 < n) offs[base + 0] = excl;
    if (base + 1 < n) offs[base + 1] = excl + v0;
    if (base + 2 < n) offs[base + 2] = excl + v0 + v1;
    if (base + 3 < n) offs[base + 3] = excl + v0 + v1 + v2;
    if (tid == THREADS - 1) bsum[blockIdx.x] = wo + incl;
}

__global__ void scan2_kernel(int* __restrict__ bsum, int nb) {
    int tid = threadIdx.x;
    int base = tid * 4;
    int v0 = 0, v1 = 0, v2 = 0, v3 = 0;
    if (base + 0 < nb) v0 = bsum[base + 0];
    if (base + 1 < nb) v1 = bsum[base + 1];
    if (base + 2 < nb) v2 = bsum[base + 2];
    if (base + 3 < nb) v3 = bsum[base + 3];
    int ts = v0 + v1 + v2 + v3;
    int lane = tid & 63;
    int incl = ts;
    #pragma unroll
    for (int off = 1; off < 64; off <<= 1) {
        int t = __shfl_up(incl, off, 64);
        if (lane >= off) incl += t;
    }
    __shared__ int wsum[4];
    int w = tid >> 6;
    if (lane == 63) wsum[w] = incl;
    __syncthreads();
    int wo = 0;
    for (int i = 0; i < w; ++i) wo += wsum[i];
    int excl = wo + incl - ts;
    if (base + 0 < nb) bsum[base + 0] = excl;
    if (base + 1 < nb) bsum[base + 1] = excl + v0;
    if (base + 2 < nb) bsum[base + 2] = excl + v0 + v1;
    if (base + 3 < nb) bsum[base + 3] = excl + v0 + v1 + v2;
    if (tid == THREADS - 1) bsum[nb] = wo + incl;
}

__global__ void scan3_kernel(int* __restrict__ offs, const int* __restrict__ bsum,
                             int* __restrict__ cur, int n) {
    int i = blockIdx.x * blockDim.x + threadIdx.x;
    if (i < n) {
        int v = offs[i] + bsum[i >> 10];
        offs[i] = v;
        cur[i] = v;
    }
    if (i == 0) offs[n] = bsum[(n + 1023) >> 10];
}

// ---------------- converts ----------------

__global__ void cvt_bf16_kernel(const float4* __restrict__ in, uint4* __restrict__ out, int n8) {
    int i = blockIdx.x * blockDim.x + threadIdx.x;
    if (i >= n8) return;
    float4 a = in[2 * i], b = in[2 * i + 1];
    uint4 o;
    o.x = (unsigned)f2bf(a.x) | ((unsigned)f2bf(a.y) << 16);
    o.y = (unsigned)f2bf(a.z) | ((unsigned)f2bf(a.w) << 16);
    o.z = (unsigned)f2bf(b.x) | ((unsigned)f2bf(b.y) << 16);
    o.w = (unsigned)f2bf(b.z) | ((unsigned)f2bf(b.w) << 16);
    out[i] = o;
}

// W (f32 [256][256]) -> MFMA B-fragment order (bf16)
__global__ void cvt_W_pack_kernel(const float* __restrict__ W, unsigned short* __restrict__ WbP) {
    int f = blockIdx.x * blockDim.x + threadIdx.x;
    if (f >= 8192) return;
    int l = f & 63, nt = (f >> 6) & 15, k0i = f >> 10;
    int r = nt * 16 + (l & 15);
    int koff = k0i * 32 + 8 * (l >> 4);
    const float4* s = reinterpret_cast<const float4*>(W + r * 256 + koff);
    float4 a = s[0], b = s[1];
    uint4 o;
    o.x = (unsigned)f2bf(a.x) | ((unsigned)f2bf(a.y) << 16);
    o.y = (unsigned)f2bf(a.z) | ((unsigned)f2bf(a.w) << 16);
    o.z = (unsigned)f2bf(b.x) | ((unsigned)f2bf(b.y) << 16);
    o.w = (unsigned)f2bf(b.z) | ((unsigned)f2bf(b.w) << 16);
    reinterpret_cast<uint4*>(WbP)[f] = o;
}

// ---------------- SpMM: one wave64 per node, bf16 gathers, x8 unroll ----------------
template<int OUT_BF16>
__global__ void spmm_bf16_kernel(const uint2* __restrict__ xb, const int* __restrict__ offs,
                                 const int2* __restrict__ pr, void* __restrict__ outp,
                                 int nnodes) {
    int wid = (blockIdx.x * blockDim.x + threadIdx.x) >> 6;
    int lane = threadIdx.x & 63;
    if (wid >= nnodes) return;
    int s = offs[wid], e = offs[wid + 1];
    float a0 = 0.f, a1 = 0.f, a2 = 0.f, a3 = 0.f;
    int i = s;
    if (i < e && (i & 1)) {
        int2 p = pr[i];
        uint2 xv = xb[(size_t)p.x * 64 + lane];
        float v = __int_as_float(p.y);
        a0 = fmaf(v, bf2f_lo(xv.x), a0); a1 = fmaf(v, bf2f_hi(xv.x), a1);
        a2 = fmaf(v, bf2f_lo(xv.y), a2); a3 = fmaf(v, bf2f_hi(xv.y), a3);
        ++i;
    }
    for (; i + 8 <= e; i += 8) {
        int4 pa = *reinterpret_cast<const int4*>(pr + i);
        int4 pb = *reinterpret_cast<const int4*>(pr + i + 2);
        int4 pc = *reinterpret_cast<const int4*>(pr + i + 4);
        int4 pd = *reinterpret_cast<const int4*>(pr + i + 6);
        uint2 x0 = xb[(size_t)pa.x * 64 + lane];
        uint2 x1 = xb[(size_t)pa.z * 64 + lane];
        uint2 x2 = xb[(size_t)pb.x * 64 + lane];
        uint2 x3 = xb[(size_t)pb.z * 64 + lane];
        uint2 x4_ = xb[(size_t)pc.x * 64 + lane];
        uint2 x5 = xb[(size_t)pc.z * 64 + lane];
        uint2 x6 = xb[(size_t)pd.x * 64 + lane];
        uint2 x7 = xb[(size_t)pd.z * 64 + lane];
        float v0 = __int_as_float(pa.y), v1 = __int_as_float(pa.w);
        float v2 = __int_as_float(pb.y), v3 = __int_as_float(pb.w);
        float v4 = __int_as_float(pc.y), v5 = __int_as_float(pc.w);
        float v6 = __int_as_float(pd.y), v7 = __int_as_float(pd.w);
        a0 = fmaf(v0, bf2f_lo(x0.x), a0); a1 = fmaf(v0, bf2f_hi(x0.x), a1);
        a2 = fmaf(v0, bf2f_lo(x0.y), a2); a3 = fmaf(v0, bf2f_hi(x0.y), a3);
        a0 = fmaf(v1, bf2f_lo(x1.x), a0); a1 = fmaf(v1, bf2f_hi(x1.x), a1);
        a2 = fmaf(v1, bf2f_lo(x1.y), a2); a3 = fmaf(v1, bf2f_hi(x1.y), a3);
        a0 = fmaf(v2, bf2f_lo(x2.x), a0); a1 = fmaf(v2, bf2f_hi(x2.x), a1);
        a2 = fmaf(v2, bf2f_lo(x2.y), a2); a3 = fmaf(v2, bf2f_hi(x2.y), a3);
        a0 = fmaf(v3, bf2f_lo(x3.x), a0); a1 = fmaf(v3, bf2f_hi(x3.x), a1);
        a2 = fmaf(v3, bf2f_lo(x3.y), a2); a3 = fmaf(v3, bf2f_hi(x3.y), a3);
        a0 = fmaf(v4, bf2f_lo(x4_.x), a0); a1 = fmaf(v4, bf2f_hi(x4_.x), a1);
        a2 = fmaf(v4, bf2f_lo(x4_.y), a2); a3 = fmaf(v4, bf2f_hi(x4_.y), a3);
        a0 = fmaf(v5, bf2f_lo(x5.x), a0); a1 = fmaf(v5, bf2f_hi(x5.x), a1);
        a2 = fmaf(v5, bf2f_lo(x5.y), a2); a3 = fmaf(v5, bf2f_hi(x5.y), a3);
        a0 = fmaf(v6, bf2f_lo(x6.x), a0); a1 = fmaf(v6, bf2f_hi(x6.x), a1);
        a2 = fmaf(v6, bf2f_lo(x6.y), a2); a3 = fmaf(v6, bf2f_hi(x6.y), a3);
        a0 = fmaf(v7, bf2f_lo(x7.x), a0); a1 = fmaf(v7, bf2f_hi(x7.x), a1);
        a2 = fmaf(v7, bf2f_lo(x7.y), a2); a3 = fmaf(v7, bf2f_hi(x7.y), a3);
    }
    for (; i + 2 <= e; i += 2) {
        int4 pa = *reinterpret_cast<const int4*>(pr + i);
        uint2 x0 = xb[(size_t)pa.x * 64 + lane];
        uint2 x1 = xb[(size_t)pa.z * 64 + lane];
        float v0 = __int_as_float(pa.y), v1 = __int_as_float(pa.w);
        a0 = fmaf(v0, bf2f_lo(x0.x), a0); a1 = fmaf(v0, bf2f_hi(x0.x), a1);
        a2 = fmaf(v0, bf2f_lo(x0.y), a2); a3 = fmaf(v0, bf2f_hi(x0.y), a3);
        a0 = fmaf(v1, bf2f_lo(x1.x), a0); a1 = fmaf(v1, bf2f_hi(x1.x), a1);
        a2 = fmaf(v1, bf2f_lo(x1.y), a2); a3 = fmaf(v1, bf2f_hi(x1.y), a3);
    }
    for (; i < e; ++i) {
        int2 p = pr[i];
        uint2 xv = xb[(size_t)p.x * 64 + lane];
        float v = __int_as_float(p.y);
        a0 = fmaf(v, bf2f_lo(xv.x), a0); a1 = fmaf(v, bf2f_hi(xv.x), a1);
        a2 = fmaf(v, bf2f_lo(xv.y), a2); a3 = fmaf(v, bf2f_hi(xv.y), a3);
    }
    if (OUT_BF16) {
        ushort4 o;
        o.x = f2bf(a0); o.y = f2bf(a1); o.z = f2bf(a2); o.w = f2bf(a3);
        *reinterpret_cast<ushort4*>((unsigned short*)outp + (size_t)wid * 256 + 4 * lane) = o;
    } else {
        ((float4*)outp)[(size_t)wid * 64 + lane] = make_float4(a0, a1, a2, a3);
    }
}

__global__ void spmm_f32_kernel(const float4* __restrict__ x4, const int* __restrict__ offs,
                                const int2* __restrict__ pr, float4* __restrict__ out4,
                                int nnodes) {
    int wid = (blockIdx.x * blockDim.x + threadIdx.x) >> 6;
    int lane = threadIdx.x & 63;
    if (wid >= nnodes) return;
    int s = offs[wid], e = offs[wid + 1];
    float4 acc = make_float4(0.f, 0.f, 0.f, 0.f);
    for (int i = s; i < e; ++i) {
        int2 p = pr[i];
        float4 xv = x4[(size_t)p.x * 64 + lane];
        float v = __int_as_float(p.y);
        acc.x = fmaf(v, xv.x, acc.x); acc.y = fmaf(v, xv.y, acc.y);
        acc.z = fmaf(v, xv.z, acc.z); acc.w = fmaf(v, xv.w, acc.w);
    }
    out4[(size_t)wid * 64 + lane] = acc;
}

// ---------------- LDS-free direct MFMA GEMM (bf16 agg -> f32 out) ----------------
__launch_bounds__(256)
__global__ void gemm_direct_kernel(const unsigned short* __restrict__ aggb,
                                   const unsigned short* __restrict__ WbP,
                                   const float* __restrict__ bias,
                                   float* __restrict__ out, int n) {
    int tid = threadIdx.x, lane = tid & 63, w = tid >> 6;
    int row0 = blockIdx.x * 64 + w * 16;
    int lr = lane & 15, lg = lane >> 4;
    const unsigned short* arow = aggb + (size_t)(row0 + lr) * 256 + lg * 8;
    short8 af[8];
    #pragma unroll
    for (int k = 0; k < 8; ++k)
        af[k] = *reinterpret_cast<const short8*>(arow + k * 32);
    f32x4 acc[16];
    #pragma unroll
    for (int nt = 0; nt < 16; ++nt) acc[nt] = (f32x4){0.f, 0.f, 0.f, 0.f};
    #pragma unroll
    for (int k = 0; k < 8; ++k) {
        #pragma unroll
        for (int nt = 0; nt < 16; ++nt) {
            short8 bf_ = *reinterpret_cast<const short8*>(
                &WbP[(size_t)((k * 16 + nt) * 64 + lane) * 8]);
            acc[nt] = __builtin_amdgcn_mfma_f32_16x16x32_bf16(af[k], bf_, acc[nt], 0, 0, 0);
        }
    }
    #pragma unroll
    for (int nt = 0; nt < 16; ++nt) {
        int gc = nt * 16 + lr;
        float bv = bias[gc];
        #pragma unroll
        for (int q = 0; q < 4; ++q) {
            int gr = row0 + lg * 4 + q;
            if (gr < n) out[(size_t)gr * 256 + gc] = acc[nt][q] + bv;
        }
    }
}

// ---------------- in-place GEMM (fallback tier; f32 agg lives in d_out) ----------------
__launch_bounds__(256, 2)
__global__ void gemm_mfma_kernel(float* __restrict__ out, const unsigned short* __restrict__ Wb,
                                 const float* __restrict__ bias, int nrows) {
    __shared__ unsigned short As[64][264];
    __shared__ unsigned short Ws[256][40];
    int tid = threadIdx.x;
    int rowBase = blockIdx.x * 64;

    const float4* o4 = reinterpret_cast<const float4*>(out);
    for (int it = tid; it < 64 * 64; it += 256) {
        int r = it >> 6, c = it & 63;
        float4 v = make_float4(0.f, 0.f, 0.f, 0.f);
        int gr = rowBase + r;
        if (gr < nrows) v = o4[(size_t)gr * 64 + c];
        ushort4 w;
        w.x = f2bf(v.x); w.y = f2bf(v.y); w.z = f2bf(v.z); w.w = f2bf(v.w);
        *reinterpret_cast<ushort4*>(&As[r][c * 4]) = w;
    }

    int w = tid >> 6, lane = tid & 63;
    int lr = lane & 15, lg = lane >> 4;
    f32x4 acc[16];
    #pragma unroll
    for (int nt = 0; nt < 16; ++nt) acc[nt] = (f32x4){0.f, 0.f, 0.f, 0.f};

    for (int k0 = 0; k0 < 256; k0 += 32) {
        __syncthreads();
        for (int it = tid; it < 1024; it += 256) {
            int r = it >> 2, c = it & 3;
            uint4 v = *reinterpret_cast<const uint4*>(Wb + (size_t)r * 256 + k0 + c * 8);
            *reinterpret_cast<uint4*>(&Ws[r][c * 8]) = v;
        }
        __syncthreads();
        short8 af = *reinterpret_cast<const short8*>(&As[w * 16 + lr][k0 + 8 * lg]);
        #pragma unroll
        for (int nt = 0; nt < 16; ++nt) {
            short8 bf_ = *reinterpret_cast<const short8*>(&Ws[nt * 16 + lr][8 * lg]);
            acc[nt] = __builtin_amdgcn_mfma_f32_16x16x32_bf16(af, bf_, acc[nt], 0, 0, 0);
        }
    }

    #pragma unroll
    for (int nt = 0; nt < 16; ++nt) {
        int gc = nt * 16 + lr;
        float bv = bias[gc];
        #pragma unroll
        for (int q = 0; q < 4; ++q) {
            int gr = rowBase + w * 16 + lg * 4 + q;
            if (gr < nrows) out[(size_t)gr * 256 + gc] = acc[nt][q] + bv;
        }
    }
}

// ---------------- launch ----------------

extern "C" void kernel_launch(void* const* d_in, const int* in_sizes, int n_in,
                              void* d_out, int out_size, void* d_ws, size_t ws_size,
                              hipStream_t stream) {
    const float* x     = (const float*)d_in[0];
    const int*   erow  = (const int*)d_in[1];
    const int*   ecol  = (const int*)d_in[2];
    const float* evalv = (const float*)d_in[3];
    const float* W     = (const float*)d_in[4];
    const float* bias  = (const float*)d_in[5];
    float* out = (float*)d_out;

    int n_nodes = in_sizes[0] / 256;
    int n_edges = in_sizes[1];

    int nbkt = (n_nodes + 255) >> 8;
    int avg = n_edges / (nbkt > 0 ? nbkt : 1);
    int capB = avg + avg / 4 + 1024;

    // ---- new-path workspace layout (int units) ----
    size_t A = (size_t)((n_nodes + 63) & ~63) + 64;       // offs: n+1
    int* offs  = (int*)d_ws;
    int* gcur  = offs + A;                                // 512
    int* bcnt_ = gcur + 512;                              // 512
    int* bbase = bcnt_ + 512;                             // 513 (pad 576)
    int* bscr  = bbase + 576;                             // 512
    unsigned short* Wb  = (unsigned short*)(bscr + 512);  // 32768 ints
    unsigned short* WbP = Wb + 65536;                     // 32768 ints
    int2* pr = (int2*)(WbP + 65536);                      // E records
    int* after_pr = (int*)(pr + n_edges);

    size_t est_ints  = (size_t)nbkt * capB * 2;
    size_t aggb_ints = (size_t)n_nodes * 128;
    size_t xb_ints   = (size_t)n_nodes * 128;
    size_t alias_ints = est_ints > aggb_ints ? est_ints : aggb_ints;
    size_t head_ints = (size_t)(after_pr - (int*)d_ws);
    size_t need_new = (head_ints + alias_ints + xb_ints) * 4;
    bool new_ok = (nbkt <= 512) && (nbkt >= 1) && ws_size >= need_new;

    if (new_ok) {
        uint2* estage = (uint2*)after_pr;
        unsigned short* aggb = (unsigned short*)after_pr;            // alias (estage dead post-p2)
        unsigned short* xb = (unsigned short*)(after_pr + alias_ints);

        init_gcur512<<<2, THREADS, 0, stream>>>(gcur, capB);
        p1_sort<<<512, THREADS, 0, stream>>>(erow, ecol, evalv, gcur, estage,
                                             n_edges, nbkt, capB);
        bcnt_kernel<<<2, THREADS, 0, stream>>>(gcur, bcnt_, capB, nbkt);
        bscan_kernel<<<1, THREADS, 0, stream>>>(bcnt_, bbase, bscr, nbkt);
        p2_sort<<<nbkt, THREADS, 0, stream>>>(estage, gcur, bbase, pr, offs,
                                              capB, n_nodes, n_edges, nbkt);

        cvt_W_pack_kernel<<<32, THREADS, 0, stream>>>(W, WbP);
        int n8 = n_nodes * 32;
        cvt_bf16_kernel<<<(n8 + THREADS - 1) / THREADS, THREADS, 0, stream>>>(
            (const float4*)x, (uint4*)xb, n8);

        int spmm_blocks = (n_nodes + 3) / 4;
        spmm_bf16_kernel<1><<<spmm_blocks, THREADS, 0, stream>>>(
            (const uint2*)xb, offs, pr, aggb, n_nodes);
        int gb = (n_nodes + 63) / 64;
        gemm_direct_kernel<<<gb, THREADS, 0, stream>>>(aggb, WbP, bias, out, n_nodes);
    } else {
        // -------- fallback: round-4 path --------
        int nb = (n_nodes + 1023) >> 10;
        size_t Af = (size_t)((n_nodes + 63) & ~63);
        int* cnt   = (int*)d_ws;
        int* offsf = cnt + Af;
        int* cur   = offsf + Af;
        int* bsum  = cur + Af;
        int* wbase = bsum + (((size_t)nb + 64) & ~63ull);
        unsigned short* Wbf = (unsigned short*)wbase;
        int2* prf  = (int2*)(Wbf + 65536);
        int* aft   = (int*)(prf + n_edges);
        unsigned short* xbf = (unsigned short*)aft;
        size_t need_old = (size_t)((char*)(xbf + (size_t)n_nodes * 256) - (char*)d_ws);
        bool told = ws_size >= need_old;

        zero_kernel<<<(n_nodes + THREADS - 1) / THREADS, THREADS, 0, stream>>>(cnt, n_nodes);
        hist_part_kernel<<<2048, THREADS, 0, stream>>>(erow, cnt, n_edges, n_nodes);
        scan1_kernel<<<nb, THREADS, 0, stream>>>(cnt, offsf, bsum, n_nodes);
        scan2_kernel<<<1, THREADS, 0, stream>>>(bsum, nb);
        scan3_kernel<<<(n_nodes + THREADS - 1) / THREADS, THREADS, 0, stream>>>(offsf, bsum, cur, n_nodes);
        place_part_kernel<<<2048, THREADS, 0, stream>>>(erow, ecol, evalv, cur, prf, n_edges, n_nodes);
        cvt_bf16_kernel<<<32, THREADS, 0, stream>>>((const float4*)W, (uint4*)Wbf, 65536 / 8);

        int gb = (n_nodes + 63) / 64;
        if (told) {
            int n8 = n_nodes * 32;
            cvt_bf16_kernel<<<(n8 + THREADS - 1) / THREADS, THREADS, 0, stream>>>(
                (const float4*)x, (uint4*)xbf, n8);
            int spmm_blocks = (n_nodes + 3) / 4;
            spmm_bf16_kernel<0><<<spmm_blocks, THREADS, 0, stream>>>(
                (const uint2*)xbf, offsf, prf, out, n_nodes);
        } else {
            int spmm_blocks = (n_nodes + 3) / 4;
            spmm_f32_kernel<<<spmm_blocks, THREADS, 0, stream>>>(
                (const float4*)x, offsf, prf, (float4*)out, n_nodes);
        }
        gemm_mfma_kernel<<<gb, THREADS, 0, stream>>>(out, Wbf, bias, n_nodes);
    }
}